// Round 21
// baseline (302.177 us; speedup 1.0000x reference)
//
#include <hip/hip_runtime.h>
#include <cstdint>

// GraphNets v18 = v17 + (1) bf16 node_feat table for the random gathers
// (direct short8 fragment loads, no cvt) and (2) CSR-permuted e_perm copy
// written by the edge epilogue (scatter-WRITE) so the node msgs gather reads
// CONTIGUOUS rows (kills elist indirection + random-read latency).
// Tiered on ws_size: PERM -> NFB -> legacy CSR (v17) -> legacy atomic.
// mfma_f32_16x16x32_bf16: A lane l: row=l&15, k=(l>>4)*8+j ; B: col=l&15, same k
// C/D: col=lane&15, row=(lane>>4)*4+reg   [verified v2-v17]

typedef short short8 __attribute__((ext_vector_type(8)));
typedef float f32x4 __attribute__((ext_vector_type(4)));

#define MFMA16(a, b, c) __builtin_amdgcn_mfma_f32_16x16x32_bf16(a, b, c, 0, 0, 0)

__device__ __forceinline__ short f2bf(float x) {
    union { __bf16 b; short s; } u; u.b = (__bf16)x; return u.s;
}
__device__ __forceinline__ unsigned pkbf(float a, float b) {
    return (unsigned)(unsigned short)f2bf(a) |
           ((unsigned)(unsigned short)f2bf(b) << 16);
}
__device__ __forceinline__ short8 pack8(float4 lo, float4 hi) {
    short8 r;
    r[0] = f2bf(lo.x); r[1] = f2bf(lo.y); r[2] = f2bf(lo.z); r[3] = f2bf(lo.w);
    r[4] = f2bf(hi.x); r[5] = f2bf(hi.y); r[6] = f2bf(hi.z); r[7] = f2bf(hi.w);
    return r;
}
__device__ __forceinline__ short8 pack8v(f32x4 lo, f32x4 hi) {
    short8 r;
    r[0] = f2bf(lo[0]); r[1] = f2bf(lo[1]); r[2] = f2bf(lo[2]); r[3] = f2bf(lo[3]);
    r[4] = f2bf(hi[0]); r[5] = f2bf(hi[1]); r[6] = f2bf(hi[2]); r[7] = f2bf(hi[3]);
    return r;
}
__device__ __forceinline__ short8 zero8() {
    short8 z;
#pragma unroll
    for (int j = 0; j < 8; ++j) z[j] = 0;
    return z;
}

// ---------------------------------------------------------------------------
// Weight prep (v12 layout, verified):
//   edge: W1'[K=192] 48K @0 | We2 32K @49152 | We3 16K @81920
//   node: Wn1'[K=128] 32K @98304 | Wn2 32K @131072 | Wn3 16K @163840
// ---------------------------------------------------------------------------
__global__ __launch_bounds__(256)
void prep_weights(const float* __restrict__ We1, const float* __restrict__ We2,
                  const float* __restrict__ We3, const float* __restrict__ Wn1,
                  const float* __restrict__ Wn2, const float* __restrict__ Wn3,
                  char* __restrict__ out)
{
    const int fg = blockIdx.x * 4 + (threadIdx.x >> 6);
    if (fg >= 176) return;
    const int lane = threadIdx.x & 63;
    const float* W; int Ncols, f; size_t obase;
    if      (fg < 48)  { W = We1; Ncols = 128; f = fg;       obase = 0;      }
    else if (fg < 80)  { W = We2; Ncols = 128; f = fg - 48;  obase = 49152;  }
    else if (fg < 96)  { W = We3; Ncols = 64;  f = fg - 80;  obase = 81920;  }
    else if (fg < 128) { W = Wn1; Ncols = 128; f = fg - 96;  obase = 98304;  }
    else if (fg < 160) { W = Wn2; Ncols = 128; f = fg - 128; obase = 131072; }
    else               { W = Wn3; Ncols = 64;  f = fg - 160; obase = 163840; }
    const int NF = Ncols >> 4;
    const int kf = f / NF, nf = f - kf * NF;
    const int k0 = kf * 32 + (lane >> 4) * 8;
    const int col = nf * 16 + (lane & 15);
    union { short s[8]; uint4 u; } pk;
#pragma unroll
    for (int j = 0; j < 8; ++j) pk.s[j] = f2bf(W[(size_t)(k0 + j) * Ncols + col]);
    *(uint4*)(out + obase + ((size_t)f * 64 + lane) * 16) = pk.u;
}

// ---------------------------------------------------------------------------
// G prep (verified v12)
// ---------------------------------------------------------------------------
__global__ __launch_bounds__(256)
void prep_g(const float* __restrict__ grepr,
            const float* __restrict__ We1, const float* __restrict__ be1,
            const float* __restrict__ Wn1, const float* __restrict__ bn1,
            char* __restrict__ gout)
{
    const int gid = blockIdx.x * 256 + threadIdx.x;
    if (gid >= 1024) return;
    const int table = gid >> 9, slot = gid & 511;
    const int nf = slot >> 6, lane = slot & 63;
    const int l4 = lane >> 4, l15 = lane & 15;
    const float* W   = table ? Wn1 : We1;
    const float* bia = table ? bn1 : be1;
    const int Koff   = table ? 128 : 192;
    const int hcol = nf * 16 + l15;
    union { short s[8]; uint4 u; } r;
#pragma unroll
    for (int j = 0; j < 8; ++j) {
        short v = 0;
        if (l4 < 2) {
            const int g = l4 * 8 + j;
            float s = bia[hcol];
            for (int k = 0; k < 64; ++k)
                s += grepr[g * 64 + k] * W[(size_t)(Koff + k) * 128 + hcol];
            v = f2bf(s);
        }
        r.s[j] = v;
    }
    *(uint4*)(gout + table * 8192 + ((size_t)nf * 64 + lane) * 16) = r.u;
}

// ---------------------------------------------------------------------------
// node_feat fp32 -> bf16 table
// ---------------------------------------------------------------------------
__global__ __launch_bounds__(256)
void conv_nf(const float* __restrict__ src, short* __restrict__ dstb, int n8)
{
    const int i = blockIdx.x * 256 + threadIdx.x;
    if (i < n8) {
        const float4 a = *(const float4*)(src + (size_t)i * 8);
        const float4 b = *(const float4*)(src + (size_t)i * 8 + 4);
        *(short8*)(dstb + (size_t)i * 8) = pack8(a, b);
    }
}

// ---------------------------------------------------------------------------
// CSR build (verified v4) — fill also records epos when provided.
// ---------------------------------------------------------------------------
__global__ __launch_bounds__(256)
void hist_kernel(const int* __restrict__ dst, int* __restrict__ deg, int E)
{
    const int i = blockIdx.x * 256 + threadIdx.x;
    if (i < E) atomicAdd(&deg[dst[i]], 1);
}
__global__ __launch_bounds__(256)
void scanA_kernel(const int* __restrict__ deg, int* __restrict__ psum, int n)
{
    __shared__ int red[256];
    const int t = threadIdx.x;
    const int i = blockIdx.x * 256 + t;
    red[t] = (i < n) ? deg[i] : 0;
    __syncthreads();
    for (int s = 128; s > 0; s >>= 1) {
        if (t < s) red[t] += red[t + s];
        __syncthreads();
    }
    if (t == 0) psum[blockIdx.x] = red[0];
}
__global__ __launch_bounds__(256)
void scanB_kernel(int* __restrict__ psum, int nb)
{
    __shared__ int s[256];
    const int t = threadIdx.x;
    const int v0 = (t < nb) ? psum[t] : 0;
    s[t] = v0;
    __syncthreads();
    for (int d = 1; d < 256; d <<= 1) {
        const int v = (t >= d) ? s[t - d] : 0;
        __syncthreads();
        s[t] += v;
        __syncthreads();
    }
    if (t < nb) psum[t] = s[t] - v0;
}
__global__ __launch_bounds__(256)
void scanC_kernel(const int* __restrict__ deg, const int* __restrict__ psum,
                  int* __restrict__ start, int* __restrict__ cursor, int n)
{
    __shared__ int s[256];
    const int t = threadIdx.x;
    const int i = blockIdx.x * 256 + t;
    const int v0 = (i < n) ? deg[i] : 0;
    s[t] = v0;
    __syncthreads();
    for (int d = 1; d < 256; d <<= 1) {
        const int v = (t >= d) ? s[t - d] : 0;
        __syncthreads();
        s[t] += v;
        __syncthreads();
    }
    const int ex = s[t] - v0 + psum[blockIdx.x];
    if (i < n) { start[i] = ex; cursor[i] = ex; }
}
__global__ __launch_bounds__(256)
void fill_kernel(const int* __restrict__ dst, int* __restrict__ cursor,
                 int* __restrict__ elist, int* __restrict__ epos, int E)
{
    const int i = blockIdx.x * 256 + threadIdx.x;
    if (i < E) {
        const int d = dst[i];
        const int p = atomicAdd(&cursor[d], 1);
        elist[p] = i;
        if (epos) epos[i] = p;
    }
}

// ---------------------------------------------------------------------------
// LEGACY kernel (v17 body) — fallback tiers only.
// ---------------------------------------------------------------------------
template <int NQ, bool IS_EDGE, bool MSG_ATOMIC, bool GATHER>
__global__ __launch_bounds__(512, 2)
void mlp_v17_kernel(const float* __restrict__ feat0,
                    const float* feat1,
                    const int* __restrict__ srcIdx, const int* __restrict__ dstIdx,
                    const int* __restrict__ seg,
                    const int* __restrict__ gstart, const int* __restrict__ gend,
                    const int* __restrict__ elist,  const float* __restrict__ gsrc,
                    const char* __restrict__ Wsrc,  const char* __restrict__ Gsrc,
                    const float* __restrict__ b2,   const float* __restrict__ b3,
                    float* out, float* msgs_out, float* comb_rep,
                    int M)
{
    constexpr int KF1   = NQ * 2;
    constexpr int NFRAG = KF1 * 8 + 32 + 16;
    constexpr int HOFF  = NFRAG * 1024;
    extern __shared__ char lds[];

    const int t    = threadIdx.x;
    const int lane = t & 63;
    const int w    = t >> 6;
    const int l15  = lane & 15;
    const int l4   = lane >> 4;
    char* Hs = lds + HOFF + w * 8192;

    for (int f = t; f < NFRAG * 64; f += 512)
        *(uint4*)(lds + (size_t)f * 16) = *(const uint4*)(Wsrc + (size_t)f * 16);
    __syncthreads();

    const char* W1l = lds;
    const char* W2l = lds + (size_t)KF1 * 8 * 1024;
    const char* W3l = W2l + 32 * 1024;

    short8 gfrag[8];
#pragma unroll
    for (int nf = 0; nf < 8; ++nf)
        gfrag[nf] = *(const short8*)(Gsrc + ((size_t)nf * 64 + lane) * 16);

    f32x4 bv2q[8];
#pragma unroll
    for (int nf = 0; nf < 8; ++nf)
        bv2q[nf] = *(const f32x4*)(b2 + nf * 16 + l4 * 4);
    float bv3[4];
#pragma unroll
    for (int nf = 0; nf < 4; ++nf) bv3[nf] = b3[nf * 16 + l15];

    f32x4 acc_comb[4];
#pragma unroll
    for (int nf = 0; nf < 4; ++nf) acc_comb[nf] = f32x4{0.f, 0.f, 0.f, 0.f};

    int cig[2], cis[2], cid[2], cgs[2], cge[2];
    int nig[2], nis[2], nid[2], ngs[2], nge[2];
    auto load_idx = [&](int base, int (&ig)[2], int (&is)[2], int (&id)[2],
                        int (&gs)[2], int (&ge)[2]) {
#pragma unroll
        for (int g = 0; g < 2; ++g) {
            const int row = base + g * 16 + l15;
            ig[g] = 0; is[g] = 0; id[g] = 0; gs[g] = 0; ge[g] = 0;
            if (row < M) {
                ig[g] = seg[row];
                if (IS_EDGE) { is[g] = srcIdx[row]; id[g] = dstIdx[row]; }
                if (GATHER)  { gs[g] = gstart[row]; ge[g] = gend[row]; }
            }
        }
    };

    const int bstride = gridDim.x * 256;
    int base0 = blockIdx.x * 256 + w * 32;
    load_idx(base0, cig, cis, cid, cgs, cge);

    for (int base = base0; base < M + (int)(w * 32); base += bstride) {
        if (base >= M + 256) break;

        short8 xf[2][KF1];
#pragma unroll
        for (int g = 0; g < 2; ++g) {
            const int row = base + g * 16 + l15;
            const bool valid = row < M;
#pragma unroll
            for (int kf = 0; kf < KF1; ++kf) {
                const int c = kf >> 1;
                if (GATHER && c == 1) continue;
                float4 lo = make_float4(0.f, 0.f, 0.f, 0.f), hh = lo;
                if (valid) {
                    const float* p;
                    if (IS_EDGE) {
                        p = (c == 0) ? feat0 + (size_t)row    * 64
                          : (c == 1) ? feat1 + (size_t)cis[g] * 64
                          :            feat1 + (size_t)cid[g] * 64;
                    } else if (GATHER) {
                        p = feat0 + (size_t)row * 64;
                    } else {
                        p = (c == 0) ? feat0 + (size_t)row * 64
                          :            feat1 + (size_t)row * 64;
                    }
                    const int koff = (kf & 1) * 32 + l4 * 8;
                    lo = *(const float4*)(p + koff);
                    hh = *(const float4*)(p + koff + 4);
                }
                xf[g][kf] = pack8(lo, hh);
            }
            if constexpr (GATHER) {
                f32x4 m0 = {0,0,0,0}, m1 = m0, m2 = m0, m3 = m0;
                if (valid) {
                    for (int j = cgs[g]; j < cge[g]; ++j) {
                        const float* er = gsrc + (size_t)elist[j] * 64 + l4 * 8;
                        m0 += *(const f32x4*)(er);
                        m1 += *(const f32x4*)(er + 4);
                        m2 += *(const f32x4*)(er + 32);
                        m3 += *(const f32x4*)(er + 36);
                    }
                }
                xf[g][2] = pack8v(m0, m1);
                xf[g][3] = pack8v(m2, m3);
            }
        }
        const int ig0 = cig[0], ig1 = cig[1];

        load_idx(base + bstride, nig, nis, nid, ngs, nge);

        __builtin_amdgcn_s_setprio(1);
        f32x4 accT[2][8];
#pragma unroll
        for (int g = 0; g < 2; ++g) {
            short8 ohb;
            const int igg = g ? ig1 : ig0;
#pragma unroll
            for (int j = 0; j < 8; ++j)
                ohb[j] = (l4 * 8 + j == igg) ? (short)0x3F80 : (short)0;
#pragma unroll
            for (int nf = 0; nf < 8; ++nf)
                accT[g][nf] = MFMA16(gfrag[nf], ohb, (f32x4{0.f, 0.f, 0.f, 0.f}));
        }
#pragma unroll
        for (int kf = 0; kf < KF1; ++kf) {
#pragma unroll
            for (int nf = 0; nf < 8; ++nf) {
                short8 wf = *(const short8*)(W1l + ((size_t)(kf * 8 + nf) * 64 + lane) * 16);
                accT[0][nf] = MFMA16(wf, xf[0][kf], accT[0][nf]);
                accT[1][nf] = MFMA16(wf, xf[1][kf], accT[1][nf]);
            }
        }
#pragma unroll
        for (int g = 0; g < 2; ++g) {
            const int row = g * 16 + l15;
#pragma unroll
            for (int nf = 0; nf < 8; ++nf) {
                uint2 hw;
                hw.x = pkbf(fmaxf(accT[g][nf][0], 0.f), fmaxf(accT[g][nf][1], 0.f));
                hw.y = pkbf(fmaxf(accT[g][nf][2], 0.f), fmaxf(accT[g][nf][3], 0.f));
                const int slot = nf * 2 + (l4 >> 1);
                const int phys = slot ^ (row & 7);
                *(uint2*)(Hs + row * 256 + phys * 16 + (l4 & 1) * 8) = hw;
            }
        }

        f32x4 accT2[2][8];
#pragma unroll
        for (int g = 0; g < 2; ++g)
#pragma unroll
            for (int nf = 0; nf < 8; ++nf) accT2[g][nf] = bv2q[nf];
#pragma unroll
        for (int kf = 0; kf < 4; ++kf) {
            short8 bf[2];
#pragma unroll
            for (int g = 0; g < 2; ++g) {
                const int row = g * 16 + l15;
                const int phys = (kf * 4 + l4) ^ (row & 7);
                bf[g] = *(short8*)(Hs + row * 256 + phys * 16);
            }
#pragma unroll
            for (int nf = 0; nf < 8; ++nf) {
                short8 wf = *(const short8*)(W2l + ((size_t)(kf * 8 + nf) * 64 + lane) * 16);
                accT2[0][nf] = MFMA16(wf, bf[0], accT2[0][nf]);
                accT2[1][nf] = MFMA16(wf, bf[1], accT2[1][nf]);
            }
        }
#pragma unroll
        for (int g = 0; g < 2; ++g) {
            const int row = g * 16 + l15;
#pragma unroll
            for (int nf = 0; nf < 8; ++nf) {
                uint2 hw;
                hw.x = pkbf(fmaxf(accT2[g][nf][0], 0.f), fmaxf(accT2[g][nf][1], 0.f));
                hw.y = pkbf(fmaxf(accT2[g][nf][2], 0.f), fmaxf(accT2[g][nf][3], 0.f));
                const int slot = nf * 2 + (l4 >> 1);
                const int phys = slot ^ (row & 7);
                *(uint2*)(Hs + row * 256 + phys * 16 + (l4 & 1) * 8) = hw;
            }
        }

        f32x4 acc3[2][4];
#pragma unroll
        for (int g = 0; g < 2; ++g)
#pragma unroll
            for (int nf = 0; nf < 4; ++nf)
                acc3[g][nf] = f32x4{bv3[nf], bv3[nf], bv3[nf], bv3[nf]};
#pragma unroll
        for (int kf = 0; kf < 4; ++kf) {
            short8 af[2];
#pragma unroll
            for (int g = 0; g < 2; ++g) {
                const int row = g * 16 + l15;
                const int phys = (kf * 4 + l4) ^ (row & 7);
                af[g] = *(short8*)(Hs + row * 256 + phys * 16);
            }
#pragma unroll
            for (int nf = 0; nf < 4; ++nf) {
                short8 wf = *(const short8*)(W3l + ((size_t)(kf * 4 + nf) * 64 + lane) * 16);
                acc3[0][nf] = MFMA16(af[0], wf, acc3[0][nf]);
                acc3[1][nf] = MFMA16(af[1], wf, acc3[1][nf]);
            }
        }

#pragma unroll
        for (int g = 0; g < 2; ++g)
#pragma unroll
            for (int nf = 0; nf < 4; ++nf) {
                uint2 pw;
                pw.x = pkbf(acc3[g][nf][0], acc3[g][nf][1]);
                pw.y = pkbf(acc3[g][nf][2], acc3[g][nf][3]);
                const int featcol = nf * 16 + l15;
                const int slot = g * 2 + (l4 >> 1);
                const int phys = slot ^ (l15 & 3);
                *(uint2*)(Hs + featcol * 64 + phys * 16 + (l4 & 1) * 8) = pw;
            }
        short8 oh;
#pragma unroll
        for (int j = 0; j < 8; ++j) {
            const int srcl = (l4 & 1) * 8 + j;
            const int s0 = __shfl(ig0, srcl);
            const int s1 = __shfl(ig1, srcl);
            const int sg = (l4 < 2) ? s0 : s1;
            const int rr = base + l4 * 8 + j;
            oh[j] = (rr < M && sg == l15) ? (short)0x3F80 : (short)0;
        }
#pragma unroll
        for (int nf = 0; nf < 4; ++nf) {
            const int featcol = nf * 16 + l15;
            const int phys = l4 ^ (l15 & 3);
            short8 bp = *(short8*)(Hs + featcol * 64 + phys * 16);
            acc_comb[nf] = MFMA16(oh, bp, acc_comb[nf]);
        }
        __builtin_amdgcn_s_setprio(0);

#pragma unroll
        for (int g = 0; g < 2; ++g)
#pragma unroll
            for (int q = 0; q < 4; ++q) {
                const int grow = base + g * 16 + l4 * 4 + q;
                if (grow < M) {
                    int d = 0;
                    if (MSG_ATOMIC) d = dstIdx[grow];
#pragma unroll
                    for (int nf = 0; nf < 4; ++nf) {
                        const int col = nf * 16 + l15;
                        const float v = acc3[g][nf][q];
                        out[(size_t)grow * 64 + col] = v;
                        if constexpr (MSG_ATOMIC)
                            atomicAdd(msgs_out + (size_t)d * 64 + col, v);
                    }
                }
            }

#pragma unroll
        for (int g = 0; g < 2; ++g) {
            cig[g] = nig[g]; cis[g] = nis[g]; cid[g] = nid[g];
            cgs[g] = ngs[g]; cge[g] = nge[g];
        }
        if (base + bstride >= ((M + 255) & ~255)) break;
    }

    __syncthreads();
#pragma unroll
    for (int nf = 0; nf < 4; ++nf)
#pragma unroll
        for (int q = 0; q < 4; ++q)
            ((float*)Hs)[(l4 * 4 + q) * 64 + nf * 16 + l15] = acc_comb[nf][q];
    __syncthreads();
    float* hbase = (float*)(lds + HOFF);
    float* rep = comb_rep + (size_t)(blockIdx.x & 63) * 1024;
    for (int i = t; i < 1024; i += 512) {
        float s = 0.f;
#pragma unroll
        for (int wv = 0; wv < 8; ++wv) s += hbase[wv * 2048 + i];
        atomicAdd(rep + i, s);
    }
}

// ---------------------------------------------------------------------------
// v18 EDGE: bf16 src/dst gathers from nfb; optional e_perm scatter writes.
// ---------------------------------------------------------------------------
template <bool PERM>
__global__ __launch_bounds__(512, 2)
void mlp_edge18(const float* __restrict__ efeat,
                const short* __restrict__ nfb,
                const int* __restrict__ srcIdx, const int* __restrict__ dstIdx,
                const int* __restrict__ seg,
                const int* __restrict__ epos,
                const char* __restrict__ Wsrc, const char* __restrict__ Gsrc,
                const float* __restrict__ b2,  const float* __restrict__ b3,
                float* out, float* __restrict__ eperm, float* comb_rep,
                int M)
{
    constexpr int KF1   = 6;
    constexpr int NFRAG = 96;
    constexpr int HOFF  = NFRAG * 1024;
    extern __shared__ char lds[];

    const int t    = threadIdx.x;
    const int lane = t & 63;
    const int w    = t >> 6;
    const int l15  = lane & 15;
    const int l4   = lane >> 4;
    char* Hs = lds + HOFF + w * 8192;

    for (int f = t; f < NFRAG * 64; f += 512)
        *(uint4*)(lds + (size_t)f * 16) = *(const uint4*)(Wsrc + (size_t)f * 16);
    __syncthreads();

    const char* W1l = lds;
    const char* W2l = lds + 49152;
    const char* W3l = lds + 81920;

    short8 gfrag[8];
#pragma unroll
    for (int nf = 0; nf < 8; ++nf)
        gfrag[nf] = *(const short8*)(Gsrc + ((size_t)nf * 64 + lane) * 16);

    f32x4 bv2q[8];
#pragma unroll
    for (int nf = 0; nf < 8; ++nf)
        bv2q[nf] = *(const f32x4*)(b2 + nf * 16 + l4 * 4);
    float bv3[4];
#pragma unroll
    for (int nf = 0; nf < 4; ++nf) bv3[nf] = b3[nf * 16 + l15];

    f32x4 acc_comb[4];
#pragma unroll
    for (int nf = 0; nf < 4; ++nf) acc_comb[nf] = f32x4{0.f, 0.f, 0.f, 0.f};

    int cig[2], cis[2], cid[2];
    int nig[2], nis[2], nid[2];
    auto load_idx = [&](int base, int (&ig)[2], int (&is)[2], int (&id)[2]) {
#pragma unroll
        for (int g = 0; g < 2; ++g) {
            const int row = base + g * 16 + l15;
            ig[g] = 0; is[g] = 0; id[g] = 0;
            if (row < M) { ig[g] = seg[row]; is[g] = srcIdx[row]; id[g] = dstIdx[row]; }
        }
    };

    const int bstride = gridDim.x * 256;
    int base0 = blockIdx.x * 256 + w * 32;
    load_idx(base0, cig, cis, cid);

    for (int base = base0; base < M + (int)(w * 32); base += bstride) {
        if (base >= M + 256) break;

        // ---- gather: ef raw f32 (kf0,1) + src/dst direct bf16 (kf2..5) ----
        short8 xf[2][KF1];
        float4 raw[2][2][2];
#pragma unroll
        for (int g = 0; g < 2; ++g) {
            const int row = base + g * 16 + l15;
            const bool valid = row < M;
#pragma unroll
            for (int h = 0; h < 2; ++h) {
                const int koff = h * 32 + l4 * 8;
                if (valid) {
                    raw[g][h][0] = *(const float4*)(efeat + (size_t)row * 64 + koff);
                    raw[g][h][1] = *(const float4*)(efeat + (size_t)row * 64 + koff + 4);
                } else {
                    raw[g][h][0] = make_float4(0.f, 0.f, 0.f, 0.f);
                    raw[g][h][1] = make_float4(0.f, 0.f, 0.f, 0.f);
                }
            }
            if (valid) {
                const short* ps = nfb + (size_t)cis[g] * 64 + l4 * 8;
                xf[g][2] = *(const short8*)(ps);
                xf[g][3] = *(const short8*)(ps + 32);
                const short* pd = nfb + (size_t)cid[g] * 64 + l4 * 8;
                xf[g][4] = *(const short8*)(pd);
                xf[g][5] = *(const short8*)(pd + 32);
            } else {
                xf[g][2] = zero8(); xf[g][3] = zero8();
                xf[g][4] = zero8(); xf[g][5] = zero8();
            }
        }
#pragma unroll
        for (int g = 0; g < 2; ++g) {
            xf[g][0] = pack8(raw[g][0][0], raw[g][0][1]);
            xf[g][1] = pack8(raw[g][1][0], raw[g][1][1]);
        }
        const int ig0 = cig[0], ig1 = cig[1];

        load_idx(base + bstride, nig, nis, nid);

        __builtin_amdgcn_s_setprio(1);
        // ---- layer 1 (swapped) with G one-hot init ----
        f32x4 accT[2][8];
#pragma unroll
        for (int g = 0; g < 2; ++g) {
            short8 ohb;
            const int igg = g ? ig1 : ig0;
#pragma unroll
            for (int j = 0; j < 8; ++j)
                ohb[j] = (l4 * 8 + j == igg) ? (short)0x3F80 : (short)0;
#pragma unroll
            for (int nf = 0; nf < 8; ++nf)
                accT[g][nf] = MFMA16(gfrag[nf], ohb, (f32x4{0.f, 0.f, 0.f, 0.f}));
        }
#pragma unroll
        for (int kf = 0; kf < KF1; ++kf) {
#pragma unroll
            for (int nf = 0; nf < 8; ++nf) {
                short8 wf = *(const short8*)(W1l + ((size_t)(kf * 8 + nf) * 64 + lane) * 16);
                accT[0][nf] = MFMA16(wf, xf[0][kf], accT[0][nf]);
                accT[1][nf] = MFMA16(wf, xf[1][kf], accT[1][nf]);
            }
        }
#pragma unroll
        for (int g = 0; g < 2; ++g) {
            const int row = g * 16 + l15;
#pragma unroll
            for (int nf = 0; nf < 8; ++nf) {
                uint2 hw;
                hw.x = pkbf(fmaxf(accT[g][nf][0], 0.f), fmaxf(accT[g][nf][1], 0.f));
                hw.y = pkbf(fmaxf(accT[g][nf][2], 0.f), fmaxf(accT[g][nf][3], 0.f));
                const int slot = nf * 2 + (l4 >> 1);
                const int phys = slot ^ (row & 7);
                *(uint2*)(Hs + row * 256 + phys * 16 + (l4 & 1) * 8) = hw;
            }
        }

        // ---- layer 2 (swapped) ----
        f32x4 accT2[2][8];
#pragma unroll
        for (int g = 0; g < 2; ++g)
#pragma unroll
            for (int nf = 0; nf < 8; ++nf) accT2[g][nf] = bv2q[nf];
#pragma unroll
        for (int kf = 0; kf < 4; ++kf) {
            short8 bf[2];
#pragma unroll
            for (int g = 0; g < 2; ++g) {
                const int row = g * 16 + l15;
                const int phys = (kf * 4 + l4) ^ (row & 7);
                bf[g] = *(short8*)(Hs + row * 256 + phys * 16);
            }
#pragma unroll
            for (int nf = 0; nf < 8; ++nf) {
                short8 wf = *(const short8*)(W2l + ((size_t)(kf * 8 + nf) * 64 + lane) * 16);
                accT2[0][nf] = MFMA16(wf, bf[0], accT2[0][nf]);
                accT2[1][nf] = MFMA16(wf, bf[1], accT2[1][nf]);
            }
        }
#pragma unroll
        for (int g = 0; g < 2; ++g) {
            const int row = g * 16 + l15;
#pragma unroll
            for (int nf = 0; nf < 8; ++nf) {
                uint2 hw;
                hw.x = pkbf(fmaxf(accT2[g][nf][0], 0.f), fmaxf(accT2[g][nf][1], 0.f));
                hw.y = pkbf(fmaxf(accT2[g][nf][2], 0.f), fmaxf(accT2[g][nf][3], 0.f));
                const int slot = nf * 2 + (l4 >> 1);
                const int phys = slot ^ (row & 7);
                *(uint2*)(Hs + row * 256 + phys * 16 + (l4 & 1) * 8) = hw;
            }
        }

        // ---- layer 3 (standard) ----
        f32x4 acc3[2][4];
#pragma unroll
        for (int g = 0; g < 2; ++g)
#pragma unroll
            for (int nf = 0; nf < 4; ++nf)
                acc3[g][nf] = f32x4{bv3[nf], bv3[nf], bv3[nf], bv3[nf]};
#pragma unroll
        for (int kf = 0; kf < 4; ++kf) {
            short8 af[2];
#pragma unroll
            for (int g = 0; g < 2; ++g) {
                const int row = g * 16 + l15;
                const int phys = (kf * 4 + l4) ^ (row & 7);
                af[g] = *(short8*)(Hs + row * 256 + phys * 16);
            }
#pragma unroll
            for (int nf = 0; nf < 4; ++nf) {
                short8 wf = *(const short8*)(W3l + ((size_t)(kf * 4 + nf) * 64 + lane) * 16);
                acc3[0][nf] = MFMA16(af[0], wf, acc3[0][nf]);
                acc3[1][nf] = MFMA16(af[1], wf, acc3[1][nf]);
            }
        }

        // ---- comb ----
#pragma unroll
        for (int g = 0; g < 2; ++g)
#pragma unroll
            for (int nf = 0; nf < 4; ++nf) {
                uint2 pw;
                pw.x = pkbf(acc3[g][nf][0], acc3[g][nf][1]);
                pw.y = pkbf(acc3[g][nf][2], acc3[g][nf][3]);
                const int featcol = nf * 16 + l15;
                const int slot = g * 2 + (l4 >> 1);
                const int phys = slot ^ (l15 & 3);
                *(uint2*)(Hs + featcol * 64 + phys * 16 + (l4 & 1) * 8) = pw;
            }
        short8 oh;
#pragma unroll
        for (int j = 0; j < 8; ++j) {
            const int srcl = (l4 & 1) * 8 + j;
            const int s0 = __shfl(ig0, srcl);
            const int s1 = __shfl(ig1, srcl);
            const int sg = (l4 < 2) ? s0 : s1;
            const int rr = base + l4 * 8 + j;
            oh[j] = (rr < M && sg == l15) ? (short)0x3F80 : (short)0;
        }
#pragma unroll
        for (int nf = 0; nf < 4; ++nf) {
            const int featcol = nf * 16 + l15;
            const int phys = l4 ^ (l15 & 3);
            short8 bp = *(short8*)(Hs + featcol * 64 + phys * 16);
            acc_comb[nf] = MFMA16(oh, bp, acc_comb[nf]);
        }
        __builtin_amdgcn_s_setprio(0);

        // ---- epilogue: out writes + (PERM) scatter copy to CSR position ----
#pragma unroll
        for (int g = 0; g < 2; ++g)
#pragma unroll
            for (int q = 0; q < 4; ++q) {
                const int grow = base + g * 16 + l4 * 4 + q;
                if (grow < M) {
                    int p = 0;
                    if (PERM) p = epos[grow];
#pragma unroll
                    for (int nf = 0; nf < 4; ++nf) {
                        const int col = nf * 16 + l15;
                        const float v = acc3[g][nf][q];
                        out[(size_t)grow * 64 + col] = v;
                        if constexpr (PERM)
                            eperm[(size_t)p * 64 + col] = v;
                    }
                }
            }

#pragma unroll
        for (int g = 0; g < 2; ++g) {
            cig[g] = nig[g]; cis[g] = nis[g]; cid[g] = nid[g];
        }
        if (base + bstride >= ((M + 255) & ~255)) break;
    }

    __syncthreads();
#pragma unroll
    for (int nf = 0; nf < 4; ++nf)
#pragma unroll
        for (int q = 0; q < 4; ++q)
            ((float*)Hs)[(l4 * 4 + q) * 64 + nf * 16 + l15] = acc_comb[nf][q];
    __syncthreads();
    float* hbase = (float*)(lds + HOFF);
    float* rep = comb_rep + (size_t)(blockIdx.x & 63) * 1024;
    for (int i = t; i < 1024; i += 512) {
        float s = 0.f;
#pragma unroll
        for (int wv = 0; wv < 8; ++wv) s += hbase[wv * 2048 + i];
        atomicAdd(rep + i, s);
    }
}

// ---------------------------------------------------------------------------
// v18 NODE: node_feat from bf16 table; msgs from e_perm (contiguous, PERM) or
// e_out via elist (NFB tier).
// ---------------------------------------------------------------------------
template <bool PERM>
__global__ __launch_bounds__(512, 2)
void mlp_node18(const short* __restrict__ nfb,
                const int* __restrict__ seg,
                const int* __restrict__ gstart, const int* __restrict__ gend,
                const int* __restrict__ elist, const float* __restrict__ gsrc,
                const char* __restrict__ Wsrc, const char* __restrict__ Gsrc,
                const float* __restrict__ b2,  const float* __restrict__ b3,
                float* out, float* comb_rep, int M)
{
    constexpr int KF1   = 4;
    constexpr int NFRAG = 80;
    constexpr int HOFF  = NFRAG * 1024;
    extern __shared__ char lds[];

    const int t    = threadIdx.x;
    const int lane = t & 63;
    const int w    = t >> 6;
    const int l15  = lane & 15;
    const int l4   = lane >> 4;
    char* Hs = lds + HOFF + w * 8192;

    for (int f = t; f < NFRAG * 64; f += 512)
        *(uint4*)(lds + (size_t)f * 16) = *(const uint4*)(Wsrc + (size_t)f * 16);
    __syncthreads();

    const char* W1l = lds;
    const char* W2l = lds + 32768;
    const char* W3l = lds + 65536;

    short8 gfrag[8];
#pragma unroll
    for (int nf = 0; nf < 8; ++nf)
        gfrag[nf] = *(const short8*)(Gsrc + ((size_t)nf * 64 + lane) * 16);

    f32x4 bv2q[8];
#pragma unroll
    for (int nf = 0; nf < 8; ++nf)
        bv2q[nf] = *(const f32x4*)(b2 + nf * 16 + l4 * 4);
    float bv3[4];
#pragma unroll
    for (int nf = 0; nf < 4; ++nf) bv3[nf] = b3[nf * 16 + l15];

    f32x4 acc_comb[4];
#pragma unroll
    for (int nf = 0; nf < 4; ++nf) acc_comb[nf] = f32x4{0.f, 0.f, 0.f, 0.f};

    int cig[2], cgs[2], cge[2];
    int nig[2], ngs[2], nge[2];
    auto load_idx = [&](int base, int (&ig)[2], int (&gs)[2], int (&ge)[2]) {
#pragma unroll
        for (int g = 0; g < 2; ++g) {
            const int row = base + g * 16 + l15;
            ig[g] = 0; gs[g] = 0; ge[g] = 0;
            if (row < M) { ig[g] = seg[row]; gs[g] = gstart[row]; ge[g] = gend[row]; }
        }
    };

    const int bstride = gridDim.x * 256;
    int base0 = blockIdx.x * 256 + w * 32;
    load_idx(base0, cig, cgs, cge);

    for (int base = base0; base < M + (int)(w * 32); base += bstride) {
        if (base >= M + 256) break;

        short8 xf[2][KF1];
#pragma unroll
        for (int g = 0; g < 2; ++g) {
            const int row = base + g * 16 + l15;
            const bool valid = row < M;
            if (valid) {
                const short* pn = nfb + (size_t)row * 64 + l4 * 8;
                xf[g][0] = *(const short8*)(pn);
                xf[g][1] = *(const short8*)(pn + 32);
            } else {
                xf[g][0] = zero8(); xf[g][1] = zero8();
            }
            f32x4 m0 = {0,0,0,0}, m1 = m0, m2 = m0, m3 = m0;
            if (valid) {
                for (int j = cgs[g]; j < cge[g]; ++j) {
                    const float* er = PERM
                        ? gsrc + (size_t)j * 64 + l4 * 8
                        : gsrc + (size_t)elist[j] * 64 + l4 * 8;
                    m0 += *(const f32x4*)(er);
                    m1 += *(const f32x4*)(er + 4);
                    m2 += *(const f32x4*)(er + 32);
                    m3 += *(const f32x4*)(er + 36);
                }
            }
            xf[g][2] = pack8v(m0, m1);
            xf[g][3] = pack8v(m2, m3);
        }
        const int ig0 = cig[0], ig1 = cig[1];

        load_idx(base + bstride, nig, ngs, nge);

        __builtin_amdgcn_s_setprio(1);
        f32x4 accT[2][8];
#pragma unroll
        for (int g = 0; g < 2; ++g) {
            short8 ohb;
            const int igg = g ? ig1 : ig0;
#pragma unroll
            for (int j = 0; j < 8; ++j)
                ohb[j] = (l4 * 8 + j == igg) ? (short)0x3F80 : (short)0;
#pragma unroll
            for (int nf = 0; nf < 8; ++nf)
                accT[g][nf] = MFMA16(gfrag[nf], ohb, (f32x4{0.f, 0.f, 0.f, 0.f}));
        }
#pragma unroll
        for (int kf = 0; kf < KF1; ++kf) {
#pragma unroll
            for (int nf = 0; nf < 8; ++nf) {
                short8 wf = *(const short8*)(W1l + ((size_t)(kf * 8 + nf) * 64 + lane) * 16);
                accT[0][nf] = MFMA16(wf, xf[0][kf], accT[0][nf]);
                accT[1][nf] = MFMA16(wf, xf[1][kf], accT[1][nf]);
            }
        }
#pragma unroll
        for (int g = 0; g < 2; ++g) {
            const int row = g * 16 + l15;
#pragma unroll
            for (int nf = 0; nf < 8; ++nf) {
                uint2 hw;
                hw.x = pkbf(fmaxf(accT[g][nf][0], 0.f), fmaxf(accT[g][nf][1], 0.f));
                hw.y = pkbf(fmaxf(accT[g][nf][2], 0.f), fmaxf(accT[g][nf][3], 0.f));
                const int slot = nf * 2 + (l4 >> 1);
                const int phys = slot ^ (row & 7);
                *(uint2*)(Hs + row * 256 + phys * 16 + (l4 & 1) * 8) = hw;
            }
        }

        f32x4 accT2[2][8];
#pragma unroll
        for (int g = 0; g < 2; ++g)
#pragma unroll
            for (int nf = 0; nf < 8; ++nf) accT2[g][nf] = bv2q[nf];
#pragma unroll
        for (int kf = 0; kf < 4; ++kf) {
            short8 bf[2];
#pragma unroll
            for (int g = 0; g < 2; ++g) {
                const int row = g * 16 + l15;
                const int phys = (kf * 4 + l4) ^ (row & 7);
                bf[g] = *(short8*)(Hs + row * 256 + phys * 16);
            }
#pragma unroll
            for (int nf = 0; nf < 8; ++nf) {
                short8 wf = *(const short8*)(W2l + ((size_t)(kf * 8 + nf) * 64 + lane) * 16);
                accT2[0][nf] = MFMA16(wf, bf[0], accT2[0][nf]);
                accT2[1][nf] = MFMA16(wf, bf[1], accT2[1][nf]);
            }
        }
#pragma unroll
        for (int g = 0; g < 2; ++g) {
            const int row = g * 16 + l15;
#pragma unroll
            for (int nf = 0; nf < 8; ++nf) {
                uint2 hw;
                hw.x = pkbf(fmaxf(accT2[g][nf][0], 0.f), fmaxf(accT2[g][nf][1], 0.f));
                hw.y = pkbf(fmaxf(accT2[g][nf][2], 0.f), fmaxf(accT2[g][nf][3], 0.f));
                const int slot = nf * 2 + (l4 >> 1);
                const int phys = slot ^ (row & 7);
                *(uint2*)(Hs + row * 256 + phys * 16 + (l4 & 1) * 8) = hw;
            }
        }

        f32x4 acc3[2][4];
#pragma unroll
        for (int g = 0; g < 2; ++g)
#pragma unroll
            for (int nf = 0; nf < 4; ++nf)
                acc3[g][nf] = f32x4{bv3[nf], bv3[nf], bv3[nf], bv3[nf]};
#pragma unroll
        for (int kf = 0; kf < 4; ++kf) {
            short8 af[2];
#pragma unroll
            for (int g = 0; g < 2; ++g) {
                const int row = g * 16 + l15;
                const int phys = (kf * 4 + l4) ^ (row & 7);
                af[g] = *(short8*)(Hs + row * 256 + phys * 16);
            }
#pragma unroll
            for (int nf = 0; nf < 4; ++nf) {
                short8 wf = *(const short8*)(W3l + ((size_t)(kf * 4 + nf) * 64 + lane) * 16);
                acc3[0][nf] = MFMA16(af[0], wf, acc3[0][nf]);
                acc3[1][nf] = MFMA16(af[1], wf, acc3[1][nf]);
            }
        }

#pragma unroll
        for (int g = 0; g < 2; ++g)
#pragma unroll
            for (int nf = 0; nf < 4; ++nf) {
                uint2 pw;
                pw.x = pkbf(acc3[g][nf][0], acc3[g][nf][1]);
                pw.y = pkbf(acc3[g][nf][2], acc3[g][nf][3]);
                const int featcol = nf * 16 + l15;
                const int slot = g * 2 + (l4 >> 1);
                const int phys = slot ^ (l15 & 3);
                *(uint2*)(Hs + featcol * 64 + phys * 16 + (l4 & 1) * 8) = pw;
            }
        short8 oh;
#pragma unroll
        for (int j = 0; j < 8; ++j) {
            const int srcl = (l4 & 1) * 8 + j;
            const int s0 = __shfl(ig0, srcl);
            const int s1 = __shfl(ig1, srcl);
            const int sg = (l4 < 2) ? s0 : s1;
            const int rr = base + l4 * 8 + j;
            oh[j] = (rr < M && sg == l15) ? (short)0x3F80 : (short)0;
        }
#pragma unroll
        for (int nf = 0; nf < 4; ++nf) {
            const int featcol = nf * 16 + l15;
            const int phys = l4 ^ (l15 & 3);
            short8 bp = *(short8*)(Hs + featcol * 64 + phys * 16);
            acc_comb[nf] = MFMA16(oh, bp, acc_comb[nf]);
        }
        __builtin_amdgcn_s_setprio(0);

#pragma unroll
        for (int g = 0; g < 2; ++g)
#pragma unroll
            for (int q = 0; q < 4; ++q) {
                const int grow = base + g * 16 + l4 * 4 + q;
                if (grow < M) {
#pragma unroll
                    for (int nf = 0; nf < 4; ++nf)
                        out[(size_t)grow * 64 + nf * 16 + l15] = acc3[g][nf][q];
                }
            }

#pragma unroll
        for (int g = 0; g < 2; ++g) {
            cig[g] = nig[g]; cgs[g] = ngs[g]; cge[g] = nge[g];
        }
        if (base + bstride >= ((M + 255) & ~255)) break;
    }

    __syncthreads();
#pragma unroll
    for (int nf = 0; nf < 4; ++nf)
#pragma unroll
        for (int q = 0; q < 4; ++q)
            ((float*)Hs)[(l4 * 4 + q) * 64 + nf * 16 + l15] = acc_comb[nf][q];
    __syncthreads();
    float* hbase = (float*)(lds + HOFF);
    float* rep = comb_rep + (size_t)(blockIdx.x & 63) * 1024;
    for (int i = t; i < 1024; i += 512) {
        float s = 0.f;
#pragma unroll
        for (int wv = 0; wv < 8; ++wv) s += hbase[wv * 2048 + i];
        atomicAdd(rep + i, s);
    }
}

// ---------------------------------------------------------------------------
__global__ __launch_bounds__(256)
void reduce_rep_kernel(const float* __restrict__ rep, float* __restrict__ outv)
{
    const int s = blockIdx.x * 256 + threadIdx.x;   // 0..2047
    const int arr = s >> 10, idx = s & 1023;
    const float* p = rep + (size_t)arr * 65536 + idx;
    float v = 0.f;
#pragma unroll 8
    for (int r = 0; r < 64; ++r) v += p[(size_t)r * 1024];
    outv[s] = v;
}

// ---------------------------------------------------------------------------
__global__ __launch_bounds__(256)
void u_kernel(const float* __restrict__ ncomb, const float* __restrict__ ecomb,
              const float* __restrict__ gr,
              const float* __restrict__ W1, const float* __restrict__ b1,
              const float* __restrict__ W2, const float* __restrict__ b2,
              const float* __restrict__ W3, const float* __restrict__ b3,
              float* uout)
{
    __shared__ float X[16 * 192];
    __shared__ float Hs[16 * 128];
    __shared__ float H2s[16 * 128];
    const int t = threadIdx.x;
#pragma unroll
    for (int i = 0; i < 12; ++i) {
        const int idx = i * 256 + t;
        const int g = idx / 192, col = idx % 192;
        float v;
        if      (col < 64)  v = ncomb[g * 64 + col];
        else if (col < 128) v = ecomb[g * 64 + col - 64];
        else                v = gr[g * 64 + col - 128];
        X[idx] = v;
    }
    __syncthreads();
    {
        const int j = t & 127, gb = t >> 7;
        float a[8];
#pragma unroll
        for (int gi = 0; gi < 8; ++gi) a[gi] = b1[j];
        for (int k = 0; k < 192; ++k) {
            const float wv = W1[k * 128 + j];
#pragma unroll
            for (int gi = 0; gi < 8; ++gi) a[gi] += X[(gb + gi * 2) * 192 + k] * wv;
        }
#pragma unroll
        for (int gi = 0; gi < 8; ++gi) Hs[(gb + gi * 2) * 128 + j] = fmaxf(a[gi], 0.f);
    }
    __syncthreads();
    {
        const int j = t & 127, gb = t >> 7;
        float a[8];
#pragma unroll
        for (int gi = 0; gi < 8; ++gi) a[gi] = b2[j];
        for (int k = 0; k < 128; ++k) {
            const float wv = W2[k * 128 + j];
#pragma unroll
            for (int gi = 0; gi < 8; ++gi) a[gi] += Hs[(gb + gi * 2) * 128 + k] * wv;
        }
#pragma unroll
        for (int gi = 0; gi < 8; ++gi) H2s[(gb + gi * 2) * 128 + j] = fmaxf(a[gi], 0.f);
    }
    __syncthreads();
    {
        const int j = t & 63, gb = t >> 6;
        float a[4];
#pragma unroll
        for (int gi = 0; gi < 4; ++gi) a[gi] = b3[j];
        for (int k = 0; k < 128; ++k) {
            const float wv = W3[k * 64 + j];
#pragma unroll
            for (int gi = 0; gi < 4; ++gi) a[gi] += H2s[(gb + gi * 4) * 128 + k] * wv;
        }
#pragma unroll
        for (int gi = 0; gi < 4; ++gi) uout[(gb + gi * 4) * 64 + j] = a[gi];
    }
}

// ---------------------------------------------------------------------------
extern "C" void kernel_launch(void* const* d_in, const int* in_sizes, int n_in,
                              void* d_out, int out_size, void* d_ws, size_t ws_size,
                              hipStream_t stream)
{
    const float* edge_feat = (const float*)d_in[0];
    const float* node_feat = (const float*)d_in[1];
    const float* g_repr    = (const float*)d_in[2];
    const int*   src       = (const int*)d_in[3];
    const int*   dst       = (const int*)d_in[4];
    const int*   e2g       = (const int*)d_in[5];
    const int*   n2g       = (const int*)d_in[6];
    const float* We1 = (const float*)d_in[7];  const float* be1 = (const float*)d_in[8];
    const float* We2 = (const float*)d_in[9];  const float* be2 = (const float*)d_in[10];
    const float* We3 = (const float*)d_in[11]; const float* be3 = (const float*)d_in[12];
    const float* Wn1 = (const float*)d_in[13]; const float* bn1 = (const float*)d_in[14];
    const float* Wn2 = (const float*)d_in[15]; const float* bn2 = (const float*)d_in[16];
    const float* Wn3 = (const float*)d_in[17]; const float* bn3 = (const float*)d_in[18];
    const float* Wu1 = (const float*)d_in[19]; const float* bu1 = (const float*)d_in[20];
    const float* Wu2 = (const float*)d_in[21]; const float* bu2 = (const float*)d_in[22];
    const float* Wu3 = (const float*)d_in[23]; const float* bu3 = (const float*)d_in[24];

    const int E = in_sizes[3];   // 400000
    const int N = in_sizes[6];   // 50000

    float* e_out = (float*)d_out;
    float* n_out = e_out + (size_t)E * 64;
    float* u_out = n_out + (size_t)N * 64;

    // ws layout: v12 base + epos | nfb | eperm (tiered)
    char* wsc = (char*)d_ws;
    float* ecomb_rep = (float*)wsc;
    float* ncomb_rep = (float*)(wsc + 262144);
    float* ecomb     = (float*)(wsc + 524288);
    float* ncomb     = ecomb + 1024;
    char*  wf        = wsc + 532480;
    const char* WEsrc = wf;
    const char* WNsrc = wf + 98304;
    const char* Gef   = wf + 180224;
    const char* Gnf   = wf + 188416;
    int* deg    = (int*)(wsc + 745472);
    int* startA = (int*)(wsc + 945472);
    int* cursor = (int*)(wsc + 1145472);
    int* psum   = (int*)(wsc + 1345472);
    int* elist  = (int*)(wsc + 1346496);

    const size_t ws_csr  = 1346496 + (size_t)E * 4;            // elist end
    const size_t ws_epos = ws_csr + (size_t)E * 4;             // epos end
    const size_t ws_nfb  = ws_epos + (size_t)N * 64 * 2;       // nfb end
    const size_t ws_perm = ws_nfb + (size_t)E * 64 * 4;        // eperm end

    int*   epos  = (int*)(wsc + ws_csr);
    short* nfb   = (short*)(wsc + ws_epos);
    float* eperm = (float*)(wsc + ws_nfb);

    const bool csr  = ws_size >= ws_csr;
    const bool nfbk = ws_size >= ws_nfb;
    const bool perm = ws_size >= ws_perm;

    constexpr int SH_E = 98304 + 65536;   // 160 KB
    constexpr int SH_N = 81920 + 65536;   // 144 KB

    hipMemsetAsync(wsc, 0, 524288, stream);
    prep_weights<<<44, 256, 0, stream>>>(We1, We2, We3, Wn1, Wn2, Wn3, wf);
    prep_g<<<4, 256, 0, stream>>>(g_repr, We1, be1, Wn1, bn1, wf + 180224);

    if (csr) {
        hipMemsetAsync(deg, 0, (size_t)N * 4, stream);
        const int EB = (E + 255) / 256;
        const int NB = (N + 255) / 256;
        hist_kernel <<<EB, 256, 0, stream>>>(dst, deg, E);
        scanA_kernel<<<NB, 256, 0, stream>>>(deg, psum, N);
        scanB_kernel<<<1, 256, 0, stream>>>(psum, NB);
        scanC_kernel<<<NB, 256, 0, stream>>>(deg, psum, startA, cursor, N);
        fill_kernel <<<EB, 256, 0, stream>>>(dst, cursor, elist,
                                             nfbk ? epos : nullptr, E);

        if (nfbk) {
            const int n8 = N * 8;
            conv_nf<<<(n8 + 255) / 256, 256, 0, stream>>>(node_feat, nfb, n8);

            if (perm) {
                auto ek = mlp_edge18<true>;
                auto nk = mlp_node18<true>;
                hipFuncSetAttribute((const void*)ek,
                                    hipFuncAttributeMaxDynamicSharedMemorySize, SH_E);
                hipFuncSetAttribute((const void*)nk,
                                    hipFuncAttributeMaxDynamicSharedMemorySize, SH_N);
                ek<<<256, 512, SH_E, stream>>>(
                    edge_feat, nfb, src, dst, e2g, epos,
                    WEsrc, Gef, be2, be3, e_out, eperm, ecomb_rep, E);
                nk<<<256, 512, SH_N, stream>>>(
                    nfb, n2g, startA, cursor, nullptr, eperm,
                    WNsrc, Gnf, bn2, bn3, n_out, ncomb_rep, N);
            } else {
                auto ek = mlp_edge18<false>;
                auto nk = mlp_node18<false>;
                hipFuncSetAttribute((const void*)ek,
                                    hipFuncAttributeMaxDynamicSharedMemorySize, SH_E);
                hipFuncSetAttribute((const void*)nk,
                                    hipFuncAttributeMaxDynamicSharedMemorySize, SH_N);
                ek<<<256, 512, SH_E, stream>>>(
                    edge_feat, nfb, src, dst, e2g, nullptr,
                    WEsrc, Gef, be2, be3, e_out, nullptr, ecomb_rep, E);
                nk<<<256, 512, SH_N, stream>>>(
                    nfb, n2g, startA, cursor, elist, e_out,
                    WNsrc, Gnf, bn2, bn3, n_out, ncomb_rep, N);
            }
        } else {
            auto ek = mlp_v17_kernel<3, true, false, false>;
            auto nk = mlp_v17_kernel<2, false, false, true>;
            hipFuncSetAttribute((const void*)ek,
                                hipFuncAttributeMaxDynamicSharedMemorySize, SH_E);
            hipFuncSetAttribute((const void*)nk,
                                hipFuncAttributeMaxDynamicSharedMemorySize, SH_N);
            ek<<<256, 512, SH_E, stream>>>(
                edge_feat, node_feat, src, dst, e2g,
                nullptr, nullptr, nullptr, nullptr,
                WEsrc, Gef, be2, be3, e_out, nullptr, ecomb_rep, E);
            nk<<<256, 512, SH_N, stream>>>(
                node_feat, nullptr, nullptr, nullptr, n2g,
                startA, cursor, elist, e_out,
                WNsrc, Gnf, bn2, bn3, n_out, nullptr, ncomb_rep, N);
        }
    } else {
        hipMemsetAsync(n_out, 0, (size_t)N * 64 * sizeof(float), stream);
        auto ek = mlp_v17_kernel<3, true, true, false>;
        auto nk = mlp_v17_kernel<2, false, false, false>;
        hipFuncSetAttribute((const void*)ek,
                            hipFuncAttributeMaxDynamicSharedMemorySize, SH_E);
        hipFuncSetAttribute((const void*)nk,
                            hipFuncAttributeMaxDynamicSharedMemorySize, SH_N);
        ek<<<256, 512, SH_E, stream>>>(
            edge_feat, node_feat, src, dst, e2g,
            nullptr, nullptr, nullptr, nullptr,
            WEsrc, Gef, be2, be3, e_out, n_out, ecomb_rep, E);
        nk<<<256, 512, SH_N, stream>>>(
            node_feat, n_out, nullptr, nullptr, n2g,
            nullptr, nullptr, nullptr, nullptr,
            WNsrc, Gnf, bn2, bn3, n_out, nullptr, ncomb_rep, N);
    }

    reduce_rep_kernel<<<8, 256, 0, stream>>>(ecomb_rep, ecomb);
    u_kernel<<<1, 256, 0, stream>>>(ncomb, ecomb, g_repr,
                                    Wu1, bu1, Wu2, bu2, Wu3, bu3, u_out);
}

// Round 22
// 250.051 us; speedup vs baseline: 1.2085x; 1.2085x over previous
//
#include <hip/hip_runtime.h>
#include <cstdint>

// GraphNets v12 (FINAL — verified best, 248.9 us total; edge 137 us).
// 32 rows/wave, swapped-operand layers 1-2 (h^T output, packed b64 h-writes),
// g_repr folded into per-graph G table (K 256->192 / 192->128), G applied via
// one-hot MFMA from register-resident fragments. Layer 3 + comb + epilogue
// use the v8-verified standard layout. 8 waves, all weights in LDS.
// mfma_f32_16x16x32_bf16: A lane l: row=l&15, k=(l>>4)*8+j ; B: col=l&15, same k
// C/D: col=lane&15, row=(lane>>4)*4+reg   [verified v2-v18]

typedef short short8 __attribute__((ext_vector_type(8)));
typedef float f32x4 __attribute__((ext_vector_type(4)));

#define MFMA16(a, b, c) __builtin_amdgcn_mfma_f32_16x16x32_bf16(a, b, c, 0, 0, 0)

__device__ __forceinline__ short f2bf(float x) {
    union { __bf16 b; short s; } u; u.b = (__bf16)x; return u.s;
}
__device__ __forceinline__ unsigned pkbf(float a, float b) {
    return (unsigned)(unsigned short)f2bf(a) |
           ((unsigned)(unsigned short)f2bf(b) << 16);
}
__device__ __forceinline__ short8 pack8(float4 lo, float4 hi) {
    short8 r;
    r[0] = f2bf(lo.x); r[1] = f2bf(lo.y); r[2] = f2bf(lo.z); r[3] = f2bf(lo.w);
    r[4] = f2bf(hi.x); r[5] = f2bf(hi.y); r[6] = f2bf(hi.z); r[7] = f2bf(hi.w);
    return r;
}
__device__ __forceinline__ short8 pack8v(f32x4 lo, f32x4 hi) {
    short8 r;
    r[0] = f2bf(lo[0]); r[1] = f2bf(lo[1]); r[2] = f2bf(lo[2]); r[3] = f2bf(lo[3]);
    r[4] = f2bf(hi[0]); r[5] = f2bf(hi[1]); r[6] = f2bf(hi[2]); r[7] = f2bf(hi[3]);
    return r;
}

// ---------------------------------------------------------------------------
// Weight prep: frag format verified v2-v18 (1024B frags, lane-contiguous;
// identical lane map serves as A- or B-operand). Regions (rel to wf):
//   edge: W1'[K=192] 48K @0 | We2 32K @49152 | We3 16K @81920   (96 KB)
//   node: Wn1'[K=128] 32K @98304 | Wn2 32K @131072 | Wn3 16K @163840 (80 KB)
// ---------------------------------------------------------------------------
__global__ __launch_bounds__(256)
void prep_weights(const float* __restrict__ We1, const float* __restrict__ We2,
                  const float* __restrict__ We3, const float* __restrict__ Wn1,
                  const float* __restrict__ Wn2, const float* __restrict__ Wn3,
                  char* __restrict__ out)
{
    const int fg = blockIdx.x * 4 + (threadIdx.x >> 6);
    if (fg >= 176) return;
    const int lane = threadIdx.x & 63;
    const float* W; int Ncols, f; size_t obase;
    if      (fg < 48)  { W = We1; Ncols = 128; f = fg;       obase = 0;      }
    else if (fg < 80)  { W = We2; Ncols = 128; f = fg - 48;  obase = 49152;  }
    else if (fg < 96)  { W = We3; Ncols = 64;  f = fg - 80;  obase = 81920;  }
    else if (fg < 128) { W = Wn1; Ncols = 128; f = fg - 96;  obase = 98304;  }
    else if (fg < 160) { W = Wn2; Ncols = 128; f = fg - 128; obase = 131072; }
    else               { W = Wn3; Ncols = 64;  f = fg - 160; obase = 163840; }
    const int NF = Ncols >> 4;
    const int kf = f / NF, nf = f - kf * NF;
    const int k0 = kf * 32 + (lane >> 4) * 8;
    const int col = nf * 16 + (lane & 15);
    union { short s[8]; uint4 u; } pk;
#pragma unroll
    for (int j = 0; j < 8; ++j) pk.s[j] = f2bf(W[(size_t)(k0 + j) * Ncols + col]);
    *(uint4*)(out + obase + ((size_t)f * 64 + lane) * 16) = pk.u;
}

// ---------------------------------------------------------------------------
// G prep: G[g][hcol] = bias[hcol] + sum_k g_repr[g][k] * W1tail[k][hcol],
// emitted directly as 8 A-layout frags (1KB each): elem[lane][j] =
// G[(lane>>4)*8+j][nf*16+(lane&15)], zero for k>=16. Ge @0, Gn @8192.
// ---------------------------------------------------------------------------
__global__ __launch_bounds__(256)
void prep_g(const float* __restrict__ grepr,
            const float* __restrict__ We1, const float* __restrict__ be1,
            const float* __restrict__ Wn1, const float* __restrict__ bn1,
            char* __restrict__ gout)
{
    const int gid = blockIdx.x * 256 + threadIdx.x;   // 0..1023
    if (gid >= 1024) return;
    const int table = gid >> 9, slot = gid & 511;
    const int nf = slot >> 6, lane = slot & 63;
    const int l4 = lane >> 4, l15 = lane & 15;
    const float* W   = table ? Wn1 : We1;
    const float* bia = table ? bn1 : be1;
    const int Koff   = table ? 128 : 192;
    const int hcol = nf * 16 + l15;
    union { short s[8]; uint4 u; } r;
#pragma unroll
    for (int j = 0; j < 8; ++j) {
        short v = 0;
        if (l4 < 2) {
            const int g = l4 * 8 + j;
            float s = bia[hcol];
            for (int k = 0; k < 64; ++k)
                s += grepr[g * 64 + k] * W[(size_t)(Koff + k) * 128 + hcol];
            v = f2bf(s);
        }
        r.s[j] = v;
    }
    *(uint4*)(gout + table * 8192 + ((size_t)nf * 64 + lane) * 16) = r.u;
}

// ---------------------------------------------------------------------------
// CSR build: histogram -> 2-level exclusive scan -> fill.  (verified v4)
// ---------------------------------------------------------------------------
__global__ __launch_bounds__(256)
void hist_kernel(const int* __restrict__ dst, int* __restrict__ deg, int E)
{
    const int i = blockIdx.x * 256 + threadIdx.x;
    if (i < E) atomicAdd(&deg[dst[i]], 1);
}
__global__ __launch_bounds__(256)
void scanA_kernel(const int* __restrict__ deg, int* __restrict__ psum, int n)
{
    __shared__ int red[256];
    const int t = threadIdx.x;
    const int i = blockIdx.x * 256 + t;
    red[t] = (i < n) ? deg[i] : 0;
    __syncthreads();
    for (int s = 128; s > 0; s >>= 1) {
        if (t < s) red[t] += red[t + s];
        __syncthreads();
    }
    if (t == 0) psum[blockIdx.x] = red[0];
}
__global__ __launch_bounds__(256)
void scanB_kernel(int* __restrict__ psum, int nb)
{
    __shared__ int s[256];
    const int t = threadIdx.x;
    const int v0 = (t < nb) ? psum[t] : 0;
    s[t] = v0;
    __syncthreads();
    for (int d = 1; d < 256; d <<= 1) {
        const int v = (t >= d) ? s[t - d] : 0;
        __syncthreads();
        s[t] += v;
        __syncthreads();
    }
    if (t < nb) psum[t] = s[t] - v0;   // exclusive
}
__global__ __launch_bounds__(256)
void scanC_kernel(const int* __restrict__ deg, const int* __restrict__ psum,
                  int* __restrict__ start, int* __restrict__ cursor, int n)
{
    __shared__ int s[256];
    const int t = threadIdx.x;
    const int i = blockIdx.x * 256 + t;
    const int v0 = (i < n) ? deg[i] : 0;
    s[t] = v0;
    __syncthreads();
    for (int d = 1; d < 256; d <<= 1) {
        const int v = (t >= d) ? s[t - d] : 0;
        __syncthreads();
        s[t] += v;
        __syncthreads();
    }
    const int ex = s[t] - v0 + psum[blockIdx.x];
    if (i < n) { start[i] = ex; cursor[i] = ex; }
}
__global__ __launch_bounds__(256)
void fill_kernel(const int* __restrict__ dst, int* __restrict__ cursor,
                 int* __restrict__ elist, int E)
{
    const int i = blockIdx.x * 256 + threadIdx.x;
    if (i < E) {
        const int d = dst[i];
        const int p = atomicAdd(&cursor[d], 1);
        elist[p] = i;
    }
}

// ---------------------------------------------------------------------------
// v12 fused MLP. 512 thr = 8 waves, 1 block/CU. Wave owns 32 rows (2 groups
// of 16); block tile = 256 rows, grid-stride contiguous. NQ = input chunks
// (edge 3, node 2), KF1 = NQ*2.
// LDS: [W1'|W2|W3 = (KF1*8+48) KB] + 8 waves x 8KB h-slice.
// ---------------------------------------------------------------------------
template <int NQ, bool IS_EDGE, bool MSG_ATOMIC, bool GATHER>
__global__ __launch_bounds__(512, 2)
void mlp_v12_kernel(const float* __restrict__ feat0,
                    const float* feat1,
                    const int* __restrict__ srcIdx, const int* __restrict__ dstIdx,
                    const int* __restrict__ seg,
                    const int* __restrict__ gstart, const int* __restrict__ gend,
                    const int* __restrict__ elist,  const float* __restrict__ gsrc,
                    const char* __restrict__ Wsrc,  const char* __restrict__ Gsrc,
                    const float* __restrict__ b2,   const float* __restrict__ b3,
                    float* out, float* msgs_out, float* comb_rep,
                    int M, int ntiles)
{
    constexpr int KF1   = NQ * 2;
    constexpr int NFRAG = KF1 * 8 + 32 + 16;
    constexpr int HOFF  = NFRAG * 1024;
    extern __shared__ char lds[];

    const int t    = threadIdx.x;
    const int lane = t & 63;
    const int w    = t >> 6;
    const int l15  = lane & 15;
    const int l4   = lane >> 4;
    char* Hs = lds + HOFF + w * 8192;              // wave-private 8KB

    // ---- stage weight fragments ----
    for (int f = t; f < NFRAG * 64; f += 512)
        *(uint4*)(lds + (size_t)f * 16) = *(const uint4*)(Wsrc + (size_t)f * 16);
    __syncthreads();

    const char* W1l = lds;
    const char* W2l = lds + (size_t)KF1 * 8 * 1024;
    const char* W3l = W2l + 32 * 1024;

    // ---- G fragments -> registers (8 KB table, persistent) ----
    short8 gfrag[8];
#pragma unroll
    for (int nf = 0; nf < 8; ++nf)
        gfrag[nf] = *(const short8*)(Gsrc + ((size_t)nf * 64 + lane) * 16);

    // ---- hoisted biases ----
    f32x4 bv2q[8];
#pragma unroll
    for (int nf = 0; nf < 8; ++nf)
        bv2q[nf] = *(const f32x4*)(b2 + nf * 16 + l4 * 4);
    float bv3[4];
#pragma unroll
    for (int nf = 0; nf < 4; ++nf) bv3[nf] = b3[nf * 16 + l15];

    f32x4 acc_comb[4];
#pragma unroll
    for (int nf = 0; nf < 4; ++nf) acc_comb[nf] = f32x4{0.f, 0.f, 0.f, 0.f};

    // ---- index state: [group] current + next (prefetched) ----
    int cig[2], cis[2], cid[2], cgs[2], cge[2];
    int nig[2], nis[2], nid[2], ngs[2], nge[2];
    auto load_idx = [&](int base, int (&ig)[2], int (&is)[2], int (&id)[2],
                        int (&gs)[2], int (&ge)[2]) {
#pragma unroll
        for (int g = 0; g < 2; ++g) {
            const int row = base + g * 16 + l15;
            ig[g] = 0; is[g] = 0; id[g] = 0; gs[g] = 0; ge[g] = 0;
            if (row < M) {
                ig[g] = seg[row];
                if (IS_EDGE) { is[g] = srcIdx[row]; id[g] = dstIdx[row]; }
                if (GATHER)  { gs[g] = gstart[row]; ge[g] = gend[row]; }
            }
        }
    };

    const int bstride = gridDim.x * 256;
    int base0 = blockIdx.x * 256 + w * 32;
    load_idx(base0, cig, cis, cid, cgs, cge);

    for (int base = base0; base < M + (int)(w * 32); base += bstride) {
        if (base >= M + 256) break;   // safety (never taken; loop cond governs)

        // ---- gather X into B-fragment registers ----
        short8 xf[2][KF1];
#pragma unroll
        for (int g = 0; g < 2; ++g) {
            const int row = base + g * 16 + l15;
            const bool valid = row < M;
#pragma unroll
            for (int kf = 0; kf < KF1; ++kf) {
                const int c = kf >> 1;
                if (GATHER && c == 1) continue;
                float4 lo = make_float4(0.f, 0.f, 0.f, 0.f), hi = lo;
                if (valid) {
                    const float* p;
                    if (IS_EDGE) {
                        p = (c == 0) ? feat0 + (size_t)row    * 64
                          : (c == 1) ? feat1 + (size_t)cis[g] * 64
                          :            feat1 + (size_t)cid[g] * 64;
                    } else if (GATHER) {
                        p = feat0 + (size_t)row * 64;
                    } else {
                        p = (c == 0) ? feat0 + (size_t)row * 64
                          :            feat1 + (size_t)row * 64;
                    }
                    const int koff = (kf & 1) * 32 + l4 * 8;
                    lo = *(const float4*)(p + koff);
                    hi = *(const float4*)(p + koff + 4);
                }
                xf[g][kf] = pack8(lo, hi);
            }
            if constexpr (GATHER) {
                f32x4 m0 = {0,0,0,0}, m1 = m0, m2 = m0, m3 = m0;
                if (valid) {
                    for (int j = cgs[g]; j < cge[g]; ++j) {
                        const float* er = gsrc + (size_t)elist[j] * 64 + l4 * 8;
                        m0 += *(const f32x4*)(er);
                        m1 += *(const f32x4*)(er + 4);
                        m2 += *(const f32x4*)(er + 32);
                        m3 += *(const f32x4*)(er + 36);
                    }
                }
                xf[g][2] = pack8v(m0, m1);
                xf[g][3] = pack8v(m2, m3);
            }
        }
        const int ig0 = cig[0], ig1 = cig[1];
        int idst_fb[2] = { cid[0], cid[1] };
        (void)idst_fb;

        // ---- prefetch next chunk's indices ----
        load_idx(base + bstride, nig, nis, nid, ngs, nge);

        // ---- layer 1 (swapped): accT[g][nf] = h1^T frag; init via G one-hot ----
        f32x4 accT[2][8];
#pragma unroll
        for (int g = 0; g < 2; ++g) {
            short8 ohb;
            const int igg = g ? ig1 : ig0;
#pragma unroll
            for (int j = 0; j < 8; ++j)
                ohb[j] = (l4 * 8 + j == igg) ? (short)0x3F80 : (short)0;
#pragma unroll
            for (int nf = 0; nf < 8; ++nf)
                accT[g][nf] = MFMA16(gfrag[nf], ohb, (f32x4{0.f, 0.f, 0.f, 0.f}));
        }
#pragma unroll
        for (int kf = 0; kf < KF1; ++kf) {
#pragma unroll
            for (int nf = 0; nf < 8; ++nf) {
                short8 wf = *(const short8*)(W1l + ((size_t)(kf * 8 + nf) * 64 + lane) * 16);
                accT[0][nf] = MFMA16(wf, xf[0][kf], accT[0][nf]);
                accT[1][nf] = MFMA16(wf, xf[1][kf], accT[1][nf]);
            }
        }
        // h1 write: lane owns xrow=l15 (col), hcols nf*16+l4*4+q -> packed b64
#pragma unroll
        for (int g = 0; g < 2; ++g) {
            const int row = g * 16 + l15;
#pragma unroll
            for (int nf = 0; nf < 8; ++nf) {
                uint2 hw;
                hw.x = pkbf(fmaxf(accT[g][nf][0], 0.f), fmaxf(accT[g][nf][1], 0.f));
                hw.y = pkbf(fmaxf(accT[g][nf][2], 0.f), fmaxf(accT[g][nf][3], 0.f));
                const int slot = nf * 2 + (l4 >> 1);
                const int phys = slot ^ (row & 7);
                *(uint2*)(Hs + row * 256 + phys * 16 + (l4 & 1) * 8) = hw;
            }
        }

        // ---- layer 2 (swapped): B from h1 LDS, A = W2 ----
        f32x4 accT2[2][8];
#pragma unroll
        for (int g = 0; g < 2; ++g)
#pragma unroll
            for (int nf = 0; nf < 8; ++nf) accT2[g][nf] = bv2q[nf];
#pragma unroll
        for (int kf = 0; kf < 4; ++kf) {
            short8 bf[2];
#pragma unroll
            for (int g = 0; g < 2; ++g) {
                const int row = g * 16 + l15;
                const int phys = (kf * 4 + l4) ^ (row & 7);
                bf[g] = *(short8*)(Hs + row * 256 + phys * 16);
            }
#pragma unroll
            for (int nf = 0; nf < 8; ++nf) {
                short8 wf = *(const short8*)(W2l + ((size_t)(kf * 8 + nf) * 64 + lane) * 16);
                accT2[0][nf] = MFMA16(wf, bf[0], accT2[0][nf]);
                accT2[1][nf] = MFMA16(wf, bf[1], accT2[1][nf]);
            }
        }
        // h2 write (aliases h1; in-wave DS order safe)
#pragma unroll
        for (int g = 0; g < 2; ++g) {
            const int row = g * 16 + l15;
#pragma unroll
            for (int nf = 0; nf < 8; ++nf) {
                uint2 hw;
                hw.x = pkbf(fmaxf(accT2[g][nf][0], 0.f), fmaxf(accT2[g][nf][1], 0.f));
                hw.y = pkbf(fmaxf(accT2[g][nf][2], 0.f), fmaxf(accT2[g][nf][3], 0.f));
                const int slot = nf * 2 + (l4 >> 1);
                const int phys = slot ^ (row & 7);
                *(uint2*)(Hs + row * 256 + phys * 16 + (l4 & 1) * 8) = hw;
            }
        }

        // ---- layer 3 (standard): A from h2 LDS, B = W3 ----
        f32x4 acc3[2][4];
#pragma unroll
        for (int g = 0; g < 2; ++g)
#pragma unroll
            for (int nf = 0; nf < 4; ++nf)
                acc3[g][nf] = f32x4{bv3[nf], bv3[nf], bv3[nf], bv3[nf]};
#pragma unroll
        for (int kf = 0; kf < 4; ++kf) {
            short8 af[2];
#pragma unroll
            for (int g = 0; g < 2; ++g) {
                const int row = g * 16 + l15;
                const int phys = (kf * 4 + l4) ^ (row & 7);
                af[g] = *(short8*)(Hs + row * 256 + phys * 16);
            }
#pragma unroll
            for (int nf = 0; nf < 4; ++nf) {
                short8 wf = *(const short8*)(W3l + ((size_t)(kf * 4 + nf) * 64 + lane) * 16);
                acc3[0][nf] = MFMA16(af[0], wf, acc3[0][nf]);
                acc3[1][nf] = MFMA16(af[1], wf, acc3[1][nf]);
            }
        }

        // ---- comb: P staging (full 32-row K) + one-hot MFMA ----
#pragma unroll
        for (int g = 0; g < 2; ++g)
#pragma unroll
            for (int nf = 0; nf < 4; ++nf) {
                uint2 pw;
                pw.x = pkbf(acc3[g][nf][0], acc3[g][nf][1]);
                pw.y = pkbf(acc3[g][nf][2], acc3[g][nf][3]);
                const int featcol = nf * 16 + l15;
                const int slot = g * 2 + (l4 >> 1);
                const int phys = slot ^ (l15 & 3);
                *(uint2*)(Hs + featcol * 64 + phys * 16 + (l4 & 1) * 8) = pw;
            }
        short8 oh;
#pragma unroll
        for (int j = 0; j < 8; ++j) {
            const int srcl = (l4 & 1) * 8 + j;
            const int s0 = __shfl(ig0, srcl);
            const int s1 = __shfl(ig1, srcl);
            const int sg = (l4 < 2) ? s0 : s1;
            const int rr = base + l4 * 8 + j;
            oh[j] = (rr < M && sg == l15) ? (short)0x3F80 : (short)0;
        }
#pragma unroll
        for (int nf = 0; nf < 4; ++nf) {
            const int featcol = nf * 16 + l15;
            const int phys = l4 ^ (l15 & 3);
            short8 bp = *(short8*)(Hs + featcol * 64 + phys * 16);
            acc_comb[nf] = MFMA16(oh, bp, acc_comb[nf]);
        }

        // ---- epilogue ----
#pragma unroll
        for (int g = 0; g < 2; ++g)
#pragma unroll
            for (int q = 0; q < 4; ++q) {
                const int grow = base + g * 16 + l4 * 4 + q;
                if (grow < M) {
                    int d = 0;
                    if (MSG_ATOMIC) d = dstIdx[grow];
#pragma unroll
                    for (int nf = 0; nf < 4; ++nf) {
                        const int col = nf * 16 + l15;
                        const float v = acc3[g][nf][q];
                        out[(size_t)grow * 64 + col] = v;
                        if constexpr (MSG_ATOMIC)
                            atomicAdd(msgs_out + (size_t)d * 64 + col, v);
                    }
                }
            }

        // rotate prefetched indices
#pragma unroll
        for (int g = 0; g < 2; ++g) {
            cig[g] = nig[g]; cis[g] = nis[g]; cid[g] = nid[g];
            cgs[g] = ngs[g]; cge[g] = nge[g];
        }
        if (base + bstride >= ((M + 255) & ~255)) break;
    }

    // ---- comb flush: registers -> own Hs slice -> cross-wave tree ----
#pragma unroll
    for (int nf = 0; nf < 4; ++nf)
#pragma unroll
        for (int q = 0; q < 4; ++q)
            ((float*)Hs)[(l4 * 4 + q) * 64 + nf * 16 + l15] = acc_comb[nf][q];
    __syncthreads();
    float* hbase = (float*)(lds + HOFF);
    float* rep = comb_rep + (size_t)(blockIdx.x & 63) * 1024;
    for (int i = t; i < 1024; i += 512) {
        float s = 0.f;
#pragma unroll
        for (int wv = 0; wv < 8; ++wv) s += hbase[wv * 2048 + i];
        atomicAdd(rep + i, s);
    }
}

// ---------------------------------------------------------------------------
__global__ __launch_bounds__(256)
void reduce_rep_kernel(const float* __restrict__ rep, float* __restrict__ outv)
{
    const int s = blockIdx.x * 256 + threadIdx.x;   // 0..2047
    const int arr = s >> 10, idx = s & 1023;
    const float* p = rep + (size_t)arr * 65536 + idx;
    float v = 0.f;
#pragma unroll 8
    for (int r = 0; r < 64; ++r) v += p[(size_t)r * 1024];
    outv[s] = v;
}

// ---------------------------------------------------------------------------
__global__ __launch_bounds__(256)
void u_kernel(const float* __restrict__ ncomb, const float* __restrict__ ecomb,
              const float* __restrict__ gr,
              const float* __restrict__ W1, const float* __restrict__ b1,
              const float* __restrict__ W2, const float* __restrict__ b2,
              const float* __restrict__ W3, const float* __restrict__ b3,
              float* uout)
{
    __shared__ float X[16 * 192];
    __shared__ float Hs[16 * 128];
    __shared__ float H2s[16 * 128];
    const int t = threadIdx.x;
#pragma unroll
    for (int i = 0; i < 12; ++i) {
        const int idx = i * 256 + t;
        const int g = idx / 192, col = idx % 192;
        float v;
        if      (col < 64)  v = ncomb[g * 64 + col];
        else if (col < 128) v = ecomb[g * 64 + col - 64];
        else                v = gr[g * 64 + col - 128];
        X[idx] = v;
    }
    __syncthreads();
    {
        const int j = t & 127, gb = t >> 7;
        float a[8];
#pragma unroll
        for (int gi = 0; gi < 8; ++gi) a[gi] = b1[j];
        for (int k = 0; k < 192; ++k) {
            const float wv = W1[k * 128 + j];
#pragma unroll
            for (int gi = 0; gi < 8; ++gi) a[gi] += X[(gb + gi * 2) * 192 + k] * wv;
        }
#pragma unroll
        for (int gi = 0; gi < 8; ++gi) Hs[(gb + gi * 2) * 128 + j] = fmaxf(a[gi], 0.f);
    }
    __syncthreads();
    {
        const int j = t & 127, gb = t >> 7;
        float a[8];
#pragma unroll
        for (int gi = 0; gi < 8; ++gi) a[gi] = b2[j];
        for (int k = 0; k < 128; ++k) {
            const float wv = W2[k * 128 + j];
#pragma unroll
            for (int gi = 0; gi < 8; ++gi) a[gi] += Hs[(gb + gi * 2) * 128 + k] * wv;
        }
#pragma unroll
        for (int gi = 0; gi < 8; ++gi) H2s[(gb + gi * 2) * 128 + j] = fmaxf(a[gi], 0.f);
    }
    __syncthreads();
    {
        const int j = t & 63, gb = t >> 6;
        float a[4];
#pragma unroll
        for (int gi = 0; gi < 4; ++gi) a[gi] = b3[j];
        for (int k = 0; k < 128; ++k) {
            const float wv = W3[k * 64 + j];
#pragma unroll
            for (int gi = 0; gi < 4; ++gi) a[gi] += H2s[(gb + gi * 4) * 128 + k] * wv;
        }
#pragma unroll
        for (int gi = 0; gi < 4; ++gi) uout[(gb + gi * 4) * 64 + j] = a[gi];
    }
}

// ---------------------------------------------------------------------------
extern "C" void kernel_launch(void* const* d_in, const int* in_sizes, int n_in,
                              void* d_out, int out_size, void* d_ws, size_t ws_size,
                              hipStream_t stream)
{
    const float* edge_feat = (const float*)d_in[0];
    const float* node_feat = (const float*)d_in[1];
    const float* g_repr    = (const float*)d_in[2];
    const int*   src       = (const int*)d_in[3];
    const int*   dst       = (const int*)d_in[4];
    const int*   e2g       = (const int*)d_in[5];
    const int*   n2g       = (const int*)d_in[6];
    const float* We1 = (const float*)d_in[7];  const float* be1 = (const float*)d_in[8];
    const float* We2 = (const float*)d_in[9];  const float* be2 = (const float*)d_in[10];
    const float* We3 = (const float*)d_in[11]; const float* be3 = (const float*)d_in[12];
    const float* Wn1 = (const float*)d_in[13]; const float* bn1 = (const float*)d_in[14];
    const float* Wn2 = (const float*)d_in[15]; const float* bn2 = (const float*)d_in[16];
    const float* Wn3 = (const float*)d_in[17]; const float* bn3 = (const float*)d_in[18];
    const float* Wu1 = (const float*)d_in[19]; const float* bu1 = (const float*)d_in[20];
    const float* Wu2 = (const float*)d_in[21]; const float* bu2 = (const float*)d_in[22];
    const float* Wu3 = (const float*)d_in[23]; const float* bu3 = (const float*)d_in[24];

    const int E = in_sizes[3];   // 400000
    const int N = in_sizes[6];   // 50000

    float* e_out = (float*)d_out;
    float* n_out = e_out + (size_t)E * 64;
    float* u_out = n_out + (size_t)N * 64;

    // ws layout: 0 ecomb_rep 256K | 262144 ncomb_rep 256K | 524288 ecomb|ncomb
    // 532480 wf: edge 96K | node 80K @+98304 | Ge 8K @+180224 | Gn 8K @+188416
    // 745472 deg | 945472 start | 1145472 cursor | 1345472 psum | 1346496 elist
    char* wsc = (char*)d_ws;
    float* ecomb_rep = (float*)wsc;
    float* ncomb_rep = (float*)(wsc + 262144);
    float* ecomb     = (float*)(wsc + 524288);
    float* ncomb     = ecomb + 1024;
    char*  wf        = wsc + 532480;
    const char* WEsrc = wf;
    const char* WNsrc = wf + 98304;
    const char* Gef   = wf + 180224;
    const char* Gnf   = wf + 188416;
    int* deg    = (int*)(wsc + 745472);
    int* startA = (int*)(wsc + 945472);
    int* cursor = (int*)(wsc + 1145472);
    int* psum   = (int*)(wsc + 1345472);
    int* elist  = (int*)(wsc + 1346496);
    const size_t WS_NEED = 1346496 + (size_t)E * 4;
    const bool csr = (ws_size >= WS_NEED);

    constexpr int SH_E = 98304 + 65536;   // 160 KB
    constexpr int SH_N = 81920 + 65536;   // 144 KB

    hipMemsetAsync(wsc, 0, 524288, stream);
    prep_weights<<<44, 256, 0, stream>>>(We1, We2, We3, Wn1, Wn2, Wn3, wf);
    prep_g<<<4, 256, 0, stream>>>(g_repr, We1, be1, Wn1, bn1, wf + 180224);

    const int etiles = (E + 255) / 256;
    const int ntiles = (N + 255) / 256;
    (void)etiles; (void)ntiles;

    if (csr) {
        hipMemsetAsync(deg, 0, (size_t)N * 4, stream);
        const int EB = (E + 255) / 256;
        const int NB = (N + 255) / 256;
        hist_kernel <<<EB, 256, 0, stream>>>(dst, deg, E);
        scanA_kernel<<<NB, 256, 0, stream>>>(deg, psum, N);
        scanB_kernel<<<1, 256, 0, stream>>>(psum, NB);
        scanC_kernel<<<NB, 256, 0, stream>>>(deg, psum, startA, cursor, N);
        fill_kernel <<<EB, 256, 0, stream>>>(dst, cursor, elist, E);

        auto ek = mlp_v12_kernel<3, true, false, false>;
        auto nk = mlp_v12_kernel<2, false, false, true>;
        hipFuncSetAttribute((const void*)ek,
                            hipFuncAttributeMaxDynamicSharedMemorySize, SH_E);
        hipFuncSetAttribute((const void*)nk,
                            hipFuncAttributeMaxDynamicSharedMemorySize, SH_N);

        ek<<<256, 512, SH_E, stream>>>(
            edge_feat, node_feat, src, dst, e2g,
            nullptr, nullptr, nullptr, nullptr,
            WEsrc, Gef, be2, be3, e_out, nullptr, ecomb_rep, E, etiles);
        nk<<<256, 512, SH_N, stream>>>(
            node_feat, nullptr, nullptr, nullptr, n2g,
            startA, cursor, elist, e_out,
            WNsrc, Gnf, bn2, bn3, n_out, nullptr, ncomb_rep, N, ntiles);
    } else {
        hipMemsetAsync(n_out, 0, (size_t)N * 64 * sizeof(float), stream);
        auto ek = mlp_v12_kernel<3, true, true, false>;
        auto nk = mlp_v12_kernel<2, false, false, false>;
        hipFuncSetAttribute((const void*)ek,
                            hipFuncAttributeMaxDynamicSharedMemorySize, SH_E);
        hipFuncSetAttribute((const void*)nk,
                            hipFuncAttributeMaxDynamicSharedMemorySize, SH_N);
        ek<<<256, 512, SH_E, stream>>>(
            edge_feat, node_feat, src, dst, e2g,
            nullptr, nullptr, nullptr, nullptr,
            WEsrc, Gef, be2, be3, e_out, n_out, ecomb_rep, E, etiles);
        nk<<<256, 512, SH_N, stream>>>(
            node_feat, n_out, nullptr, nullptr, n2g,
            nullptr, nullptr, nullptr, nullptr,
            WNsrc, Gnf, bn2, bn3, n_out, nullptr, ncomb_rep, N, ntiles);
    }

    reduce_rep_kernel<<<8, 256, 0, stream>>>(ecomb_rep, ecomb);
    u_kernel<<<1, 256, 0, stream>>>(ncomb, ecomb, g_repr,
                                    Wu1, bu1, Wu2, bu2, Wu3, bu3, u_out);
}